// Round 3
// baseline (794.562 us; speedup 1.0000x reference)
//
#include <hip/hip_runtime.h>

// T=64, N=20000, F=8, H=32. edge_index/edge_weight dead (K=1 ChebConv).
// MFMA formulation: one wave owns 16 nodes; per step
//   Zpre/Rpre = [h | x] @ [Wh | Wx] via v_mfma_f32_16x16x32_bf16 with
//   hi/lo bf16 split (3-term) for fp32-class accuracy; gates in C-layout;
//   C->A layout transform via wave-private LDS (no __syncthreads needed:
//   same-wave DS ops are in-order).
#define T_STEPS 64
#define N_NODES 20000
#define F_IN    8
#define H_DIM   32
#define NEG_SLOPE 0.01f

typedef __attribute__((ext_vector_type(8))) short bf16x8;
typedef __attribute__((ext_vector_type(4))) float f32x4;

#define MFMA(a, b, c) __builtin_amdgcn_mfma_f32_16x16x32_bf16((a), (b), (c), 0, 0, 0)

__device__ __forceinline__ unsigned short f2bf(float f) {
    unsigned u = __float_as_uint(f);
    u += 0x7FFFu + ((u >> 16) & 1u);          // RNE
    return (unsigned short)(u >> 16);
}
__device__ __forceinline__ float bf2f(unsigned short s) {
    return __uint_as_float(((unsigned)s) << 16);
}
// pack {hi,lo} split of v into one u32 (hi in low 16)
__device__ __forceinline__ unsigned packhl(float v) {
    unsigned short h = f2bf(v);
    unsigned short l = f2bf(v - bf2f(h));
    return (unsigned)h | ((unsigned)l << 16);
}
__device__ __forceinline__ void split_pack8(const float* v, bf16x8& hi, bf16x8& lo) {
    union { unsigned u[4]; bf16x8 v8; } H, L;
#pragma unroll
    for (int p = 0; p < 4; ++p) {
        float a = v[2*p], b = v[2*p+1];
        unsigned short ha = f2bf(a), hb = f2bf(b);
        unsigned short la = f2bf(a - bf2f(ha)), lb = f2bf(b - bf2f(hb));
        H.u[p] = (unsigned)ha | ((unsigned)hb << 16);
        L.u[p] = (unsigned)la | ((unsigned)lb << 16);
    }
    hi = H.v8; lo = L.v8;
}
// 8 packed {hi,lo} words -> hi-frag and lo-frag
__device__ __forceinline__ void unpack2(uint4 a, uint4 b, bf16x8& hi, bf16x8& lo) {
    union { unsigned u[4]; bf16x8 v8; } H, L;
    unsigned w[8] = {a.x, a.y, a.z, a.w, b.x, b.y, b.z, b.w};
#pragma unroll
    for (int p = 0; p < 4; ++p) {
        unsigned w0 = w[2*p], w1 = w[2*p+1];
        H.u[p] = (w0 & 0xFFFFu) | (w1 << 16);
        L.u[p] = (w0 >> 16) | (w1 & 0xFFFF0000u);
    }
    hi = H.v8; lo = L.v8;
}
// B-frag (K=32 weight, row-major [K][H]): lane holds col, k = 8*q + j
__device__ __forceinline__ void load_wfrag32(const float* __restrict__ W, int col, int q,
                                             bf16x8& hi, bf16x8& lo) {
    float v[8];
#pragma unroll
    for (int j = 0; j < 8; ++j) v[j] = W[(8*q + j) * H_DIM + col];
    split_pack8(v, hi, lo);
}
// B-frag for K=8 weight zero-padded to K=32 (only quad 0 holds data)
__device__ __forceinline__ void load_wfrag8(const float* __restrict__ W, int col, int q,
                                            bf16x8& hi, bf16x8& lo) {
    float v[8];
#pragma unroll
    for (int j = 0; j < 8; ++j) v[j] = (q == 0) ? W[j * H_DIM + col] : 0.0f;
    split_pack8(v, hi, lo);
}

__device__ __forceinline__ float sigmoid_f(float x) { return 1.0f / (1.0f + __expf(-x)); }
__device__ __forceinline__ float tanh_f(float x)    { return 1.0f - 2.0f / (1.0f + __expf(2.0f * x)); }
__device__ __forceinline__ float leaky_f(float x)   { return x > 0.0f ? x : NEG_SLOPE * x; }

__global__ void init_out_kernel(const float* __restrict__ b2, float* __restrict__ out) {
    int t = threadIdx.x;
    if (t < T_STEPS) out[t] = b2[0];
}

__global__ __launch_bounds__(64) void rgcn_mfma_kernel(
    const float* __restrict__ x,    // [T,N,F]
    const float* __restrict__ h0,   // [N,H]
    const float* __restrict__ Wxz, const float* __restrict__ bxz,
    const float* __restrict__ Whz, const float* __restrict__ bhz,
    const float* __restrict__ Wxr, const float* __restrict__ bxr,
    const float* __restrict__ Whr, const float* __restrict__ bhr,
    const float* __restrict__ Wxh, const float* __restrict__ bxh,
    const float* __restrict__ Whh, const float* __restrict__ bhh,
    const float* __restrict__ W1,  const float* __restrict__ b1,
    const float* __restrict__ W2,
    float* __restrict__ out)        // [T] then [N,H]
{
    const int l = threadIdx.x;       // one wave per block
    const int c = l & 15;            // C-layout col / A-layout row
    const int q = l >> 4;            // quad
    const int base = blockIdx.x * 16;

    // wave-private LDS, row stride 36 words (2-way bank aliasing = free)
    __shared__ __align__(16) unsigned hbuf[16 * 36];
    __shared__ __align__(16) unsigned rbuf[16 * 36];

    // ---- constant B-fragments (hi/lo split), built once ----
    bf16x8 Bzh[2], Bzl[2], Brh[2], Brl[2], Bhh2[2], Bhl2[2];
    bf16x8 Xzh[2], Xzl[2], Xrh[2], Xrl[2], Xhh2[2], Xhl2[2];
#pragma unroll
    for (int tile = 0; tile < 2; ++tile) {
        int col = c + 16 * tile;
        load_wfrag32(Whz, col, q, Bzh[tile], Bzl[tile]);
        load_wfrag32(Whr, col, q, Brh[tile], Brl[tile]);
        load_wfrag32(Whh, col, q, Bhh2[tile], Bhl2[tile]);
        load_wfrag8 (Wxz, col, q, Xzh[tile], Xzl[tile]);
        load_wfrag8 (Wxr, col, q, Xrh[tile], Xrl[tile]);
        load_wfrag8 (Wxh, col, q, Xhh2[tile], Xhl2[tile]);
    }
    const float bz0 = bxz[c] + bhz[c],      bz1 = bxz[c+16] + bhz[c+16];
    const float br0 = bxr[c] + bhr[c],      br1 = bxr[c+16] + bhr[c+16];
    const float bh0 = bxh[c] + bhh[c],      bh1 = bxh[c+16] + bhh[c+16];
    const float w1a = W1[c], w1b = W1[c+16], b1s = b1[0];
    float w2v[4];
#pragma unroll
    for (int i = 0; i < 4; ++i) w2v[i] = W2[base + 4*q + i];

    // ---- h state in C-layout: lane holds rows 4q+i, cols c and c+16 ----
    f32x4 h0v, h1v;
#pragma unroll
    for (int i = 0; i < 4; ++i) {
        h0v[i] = h0[(base + 4*q + i) * H_DIM + c];
        h1v[i] = h0[(base + 4*q + i) * H_DIM + c + 16];
    }

    // ---- x for t=0 (A-layout source: quad 0 lane m holds x[m][0..7]) ----
    float4 xA = {0,0,0,0}, xB = {0,0,0,0};
    if (q == 0) {
        const float4* xp = (const float4*)(x + (size_t)(base + c) * F_IN);
        xA = xp[0]; xB = xp[1];
    }

#pragma unroll 1
    for (int t = 0; t < T_STEPS; ++t) {
        // prefetch next step's x
        float4 xnA = xA, xnB = xB;
        if (t + 1 < T_STEPS && q == 0) {
            const float4* xp = (const float4*)(x + (size_t)(t + 1) * (N_NODES * F_IN)
                                                 + (size_t)(base + c) * F_IN);
            xnA = xp[0]; xnB = xp[1];
        }

        // h (C-layout) -> LDS packed {hi,lo}
#pragma unroll
        for (int i = 0; i < 4; ++i) {
            int row = 4*q + i;
            hbuf[row * 36 + c]      = packhl(h0v[i]);
            hbuf[row * 36 + c + 16] = packhl(h1v[i]);
        }
        asm volatile("" ::: "memory");  // same-wave DS ops are in-order
        // A-frag of h: lane row = c, k = 8q..8q+7
        const uint4* hp = (const uint4*)&hbuf[c * 36 + 8 * q];
        uint4 ha4 = hp[0], hb4 = hp[1];
        bf16x8 ahh, ahl; unpack2(ha4, hb4, ahh, ahl);

        // x A-frag (quads 1-3 are zero)
        float xv[8] = {xA.x, xA.y, xA.z, xA.w, xB.x, xB.y, xB.z, xB.w};
        bf16x8 axh, axl; split_pack8(xv, axh, axl);

        // ---- z, r pre-activations (biases seeded in acc) ----
        f32x4 az0 = {bz0,bz0,bz0,bz0}, az1 = {bz1,bz1,bz1,bz1};
        f32x4 ar0 = {br0,br0,br0,br0}, ar1 = {br1,br1,br1,br1};
        az0 = MFMA(ahh, Bzh[0], az0); az1 = MFMA(ahh, Bzh[1], az1);
        ar0 = MFMA(ahh, Brh[0], ar0); ar1 = MFMA(ahh, Brh[1], ar1);
        az0 = MFMA(ahl, Bzh[0], az0); az1 = MFMA(ahl, Bzh[1], az1);
        ar0 = MFMA(ahl, Brh[0], ar0); ar1 = MFMA(ahl, Brh[1], ar1);
        az0 = MFMA(ahh, Bzl[0], az0); az1 = MFMA(ahh, Bzl[1], az1);
        ar0 = MFMA(ahh, Brl[0], ar0); ar1 = MFMA(ahh, Brl[1], ar1);
        az0 = MFMA(axh, Xzh[0], az0); az1 = MFMA(axh, Xzh[1], az1);
        ar0 = MFMA(axh, Xrh[0], ar0); ar1 = MFMA(axh, Xrh[1], ar1);
        az0 = MFMA(axl, Xzh[0], az0); az1 = MFMA(axl, Xzh[1], az1);
        ar0 = MFMA(axl, Xrh[0], ar0); ar1 = MFMA(axl, Xrh[1], ar1);
        az0 = MFMA(axh, Xzl[0], az0); az1 = MFMA(axh, Xzl[1], az1);
        ar0 = MFMA(axh, Xrl[0], ar0); ar1 = MFMA(axh, Xrl[1], ar1);

        f32x4 zv0, zv1, rv0, rv1;
#pragma unroll
        for (int i = 0; i < 4; ++i) {
            zv0[i] = sigmoid_f(az0[i]); zv1[i] = sigmoid_f(az1[i]);
            rv0[i] = sigmoid_f(ar0[i]); rv1[i] = sigmoid_f(ar1[i]);
        }

        // r*h (C-layout) -> LDS -> A-frag
#pragma unroll
        for (int i = 0; i < 4; ++i) {
            int row = 4*q + i;
            rbuf[row * 36 + c]      = packhl(rv0[i] * h0v[i]);
            rbuf[row * 36 + c + 16] = packhl(rv1[i] * h1v[i]);
        }
        asm volatile("" ::: "memory");
        const uint4* rp = (const uint4*)&rbuf[c * 36 + 8 * q];
        uint4 ra4 = rp[0], rb4 = rp[1];
        bf16x8 arh, arl; unpack2(ra4, rb4, arh, arl);

        // ---- h_tilde pre-activation ----
        f32x4 ah0 = {bh0,bh0,bh0,bh0}, ah1 = {bh1,bh1,bh1,bh1};
        ah0 = MFMA(arh, Bhh2[0], ah0); ah1 = MFMA(arh, Bhh2[1], ah1);
        ah0 = MFMA(arl, Bhh2[0], ah0); ah1 = MFMA(arl, Bhh2[1], ah1);
        ah0 = MFMA(arh, Bhl2[0], ah0); ah1 = MFMA(arh, Bhl2[1], ah1);
        ah0 = MFMA(axh, Xhh2[0], ah0); ah1 = MFMA(axh, Xhh2[1], ah1);
        ah0 = MFMA(axl, Xhh2[0], ah0); ah1 = MFMA(axl, Xhh2[1], ah1);
        ah0 = MFMA(axh, Xhl2[0], ah0); ah1 = MFMA(axh, Xhl2[1], ah1);

        // blend
#pragma unroll
        for (int i = 0; i < 4; ++i) {
            float th0 = tanh_f(ah0[i]);
            float th1 = tanh_f(ah1[i]);
            h0v[i] = zv0[i] * h0v[i] + (1.0f - zv0[i]) * th0;
            h1v[i] = zv1[i] * h1v[i] + (1.0f - zv1[i]) * th1;
        }

        // ---- fused head: leaky -> @W1 -> leaky -> @W2, wave reduce ----
        float rsum[4];
#pragma unroll
        for (int i = 0; i < 4; ++i)
            rsum[i] = leaky_f(h0v[i]) * w1a + leaky_f(h1v[i]) * w1b;
#pragma unroll
        for (int m = 1; m <= 8; m <<= 1) {
#pragma unroll
            for (int i = 0; i < 4; ++i) rsum[i] += __shfl_xor(rsum[i], m);
        }
        float s = 0.0f;
#pragma unroll
        for (int i = 0; i < 4; ++i) s += leaky_f(rsum[i] + b1s) * w2v[i];
        s += __shfl_xor(s, 16);
        s += __shfl_xor(s, 32);
        if (l == 0) atomicAdd(&out[t], s);

        xA = xnA; xB = xnB;
    }

    // h_fin
#pragma unroll
    for (int i = 0; i < 4; ++i) {
        out[T_STEPS + (base + 4*q + i) * H_DIM + c]      = h0v[i];
        out[T_STEPS + (base + 4*q + i) * H_DIM + c + 16] = h1v[i];
    }
}

extern "C" void kernel_launch(void* const* d_in, const int* in_sizes, int n_in,
                              void* d_out, int out_size, void* d_ws, size_t ws_size,
                              hipStream_t stream) {
    const float* x    = (const float*)d_in[0];
    // d_in[1] edge_index (int64), d_in[2] edge_weight: dead for K=1 ChebConv
    const float* h0   = (const float*)d_in[3];
    const float* Wxz  = (const float*)d_in[4];
    const float* bxz  = (const float*)d_in[5];
    const float* Whz  = (const float*)d_in[6];
    const float* bhz  = (const float*)d_in[7];
    const float* Wxr  = (const float*)d_in[8];
    const float* bxr  = (const float*)d_in[9];
    const float* Whr  = (const float*)d_in[10];
    const float* bhr  = (const float*)d_in[11];
    const float* Wxh  = (const float*)d_in[12];
    const float* bxh  = (const float*)d_in[13];
    const float* Whh  = (const float*)d_in[14];
    const float* bhh  = (const float*)d_in[15];
    const float* W1   = (const float*)d_in[16];
    const float* b1   = (const float*)d_in[17];
    const float* W2   = (const float*)d_in[18];
    const float* b2   = (const float*)d_in[19];
    float* out = (float*)d_out;

    init_out_kernel<<<1, 64, 0, stream>>>(b2, out);

    const int grid = N_NODES / 16;  // 1250 one-wave blocks, exact
    rgcn_mfma_kernel<<<grid, 64, 0, stream>>>(
        x, h0, Wxz, bxz, Whz, bhz, Wxr, bxr, Whr, bhr,
        Wxh, bxh, Whh, bhh, W1, b1, W2, out);
}

// Round 4
// 318.158 us; speedup vs baseline: 2.4974x; 2.4974x over previous
//
#include <hip/hip_runtime.h>

// T=64, N=20000, F=8, H=32. edge_index/edge_weight dead (K=1 ChebConv).
// MFMA formulation: one wave owns 16 nodes; per step
//   Zpre/Rpre = [h | x] @ [Wh | Wx] via v_mfma_f32_16x16x32_bf16 with
//   hi/lo bf16 split (3-term) for fp32-class accuracy; gates in C-layout;
//   C->A layout transform via wave-private LDS (same-wave DS ops in-order,
//   no __syncthreads). Head scalar accumulated in per-block LDS; ONE
//   cacheline-padded global atomic per t per block at kernel end (R3's
//   per-step same-address atomics were the 694us bottleneck).
#define T_STEPS 64
#define N_NODES 20000
#define F_IN    8
#define H_DIM   32
#define NEG_SLOPE 0.01f
#define WS_STRIDE 32   // floats; 128B = one cacheline per t

typedef __attribute__((ext_vector_type(8))) short bf16x8;
typedef __attribute__((ext_vector_type(4))) float f32x4;

#define MFMA(a, b, c) __builtin_amdgcn_mfma_f32_16x16x32_bf16((a), (b), (c), 0, 0, 0)

__device__ __forceinline__ unsigned short f2bf(float f) {
    unsigned u = __float_as_uint(f);
    u += 0x7FFFu + ((u >> 16) & 1u);          // RNE
    return (unsigned short)(u >> 16);
}
__device__ __forceinline__ float bf2f(unsigned short s) {
    return __uint_as_float(((unsigned)s) << 16);
}
// pack {hi,lo} split of v into one u32 (hi in low 16)
__device__ __forceinline__ unsigned packhl(float v) {
    unsigned short h = f2bf(v);
    unsigned short l = f2bf(v - bf2f(h));
    return (unsigned)h | ((unsigned)l << 16);
}
__device__ __forceinline__ void split_pack8(const float* v, bf16x8& hi, bf16x8& lo) {
    union { unsigned u[4]; bf16x8 v8; } H, L;
#pragma unroll
    for (int p = 0; p < 4; ++p) {
        float a = v[2*p], b = v[2*p+1];
        unsigned short ha = f2bf(a), hb = f2bf(b);
        unsigned short la = f2bf(a - bf2f(ha)), lb = f2bf(b - bf2f(hb));
        H.u[p] = (unsigned)ha | ((unsigned)hb << 16);
        L.u[p] = (unsigned)la | ((unsigned)lb << 16);
    }
    hi = H.v8; lo = L.v8;
}
// 8 packed {hi,lo} words -> hi-frag and lo-frag
__device__ __forceinline__ void unpack2(uint4 a, uint4 b, bf16x8& hi, bf16x8& lo) {
    union { unsigned u[4]; bf16x8 v8; } H, L;
    unsigned w[8] = {a.x, a.y, a.z, a.w, b.x, b.y, b.z, b.w};
#pragma unroll
    for (int p = 0; p < 4; ++p) {
        unsigned w0 = w[2*p], w1 = w[2*p+1];
        H.u[p] = (w0 & 0xFFFFu) | (w1 << 16);
        L.u[p] = (w0 >> 16) | (w1 & 0xFFFF0000u);
    }
    hi = H.v8; lo = L.v8;
}
// B-frag (K=32 weight, row-major [K][H]): lane holds col, k = 8*q + j
__device__ __forceinline__ void load_wfrag32(const float* __restrict__ W, int col, int q,
                                             bf16x8& hi, bf16x8& lo) {
    float v[8];
#pragma unroll
    for (int j = 0; j < 8; ++j) v[j] = W[(8*q + j) * H_DIM + col];
    split_pack8(v, hi, lo);
}
// B-frag for K=8 weight zero-padded to K=32 (only quad 0 holds data)
__device__ __forceinline__ void load_wfrag8(const float* __restrict__ W, int col, int q,
                                            bf16x8& hi, bf16x8& lo) {
    float v[8];
#pragma unroll
    for (int j = 0; j < 8; ++j) v[j] = (q == 0) ? W[j * H_DIM + col] : 0.0f;
    split_pack8(v, hi, lo);
}

__device__ __forceinline__ float sigmoid_f(float x) { return 1.0f / (1.0f + __expf(-x)); }
__device__ __forceinline__ float tanh_f(float x)    { return 1.0f - 2.0f / (1.0f + __expf(2.0f * x)); }
__device__ __forceinline__ float leaky_f(float x)   { return x > 0.0f ? x : NEG_SLOPE * x; }

__global__ void init_ws_kernel(float* __restrict__ ws) {
    int i = blockIdx.x * blockDim.x + threadIdx.x;
    if (i < T_STEPS * WS_STRIDE) ws[i] = 0.0f;
}

__global__ void final_kernel(const float* __restrict__ ws, const float* __restrict__ b2,
                             float* __restrict__ out) {
    int t = threadIdx.x;
    if (t < T_STEPS) out[t] = ws[t * WS_STRIDE] + b2[0];
}

__global__ __launch_bounds__(64) void rgcn_mfma_kernel(
    const float* __restrict__ x,    // [T,N,F]
    const float* __restrict__ h0,   // [N,H]
    const float* __restrict__ Wxz, const float* __restrict__ bxz,
    const float* __restrict__ Whz, const float* __restrict__ bhz,
    const float* __restrict__ Wxr, const float* __restrict__ bxr,
    const float* __restrict__ Whr, const float* __restrict__ bhr,
    const float* __restrict__ Wxh, const float* __restrict__ bxh,
    const float* __restrict__ Whh, const float* __restrict__ bhh,
    const float* __restrict__ W1,  const float* __restrict__ b1,
    const float* __restrict__ W2,
    float* __restrict__ ws,         // [T * WS_STRIDE] accumulators (pre-zeroed)
    float* __restrict__ out)        // [T] then [N,H]
{
    const int l = threadIdx.x;       // one wave per block
    const int c = l & 15;            // C-layout col / A-layout row
    const int q = l >> 4;            // quad
    const int base = blockIdx.x * 16;

    // wave-private LDS, row stride 36 words
    __shared__ __align__(16) unsigned hbuf[16 * 36];
    __shared__ __align__(16) unsigned rbuf[16 * 36];
    __shared__ float outacc[T_STEPS];

    // ---- constant B-fragments (hi/lo split), built once ----
    bf16x8 Bzh[2], Bzl[2], Brh[2], Brl[2], Bhh2[2], Bhl2[2];
    bf16x8 Xzh[2], Xzl[2], Xrh[2], Xrl[2], Xhh2[2], Xhl2[2];
#pragma unroll
    for (int tile = 0; tile < 2; ++tile) {
        int col = c + 16 * tile;
        load_wfrag32(Whz, col, q, Bzh[tile], Bzl[tile]);
        load_wfrag32(Whr, col, q, Brh[tile], Brl[tile]);
        load_wfrag32(Whh, col, q, Bhh2[tile], Bhl2[tile]);
        load_wfrag8 (Wxz, col, q, Xzh[tile], Xzl[tile]);
        load_wfrag8 (Wxr, col, q, Xrh[tile], Xrl[tile]);
        load_wfrag8 (Wxh, col, q, Xhh2[tile], Xhl2[tile]);
    }
    const float bz0 = bxz[c] + bhz[c],      bz1 = bxz[c+16] + bhz[c+16];
    const float br0 = bxr[c] + bhr[c],      br1 = bxr[c+16] + bhr[c+16];
    const float bh0 = bxh[c] + bhh[c],      bh1 = bxh[c+16] + bhh[c+16];
    const float w1a = W1[c], w1b = W1[c+16], b1s = b1[0];
    float w2v[4];
#pragma unroll
    for (int i = 0; i < 4; ++i) w2v[i] = W2[base + 4*q + i];

    // ---- h state in C-layout: lane holds rows 4q+i, cols c and c+16 ----
    f32x4 h0v, h1v;
#pragma unroll
    for (int i = 0; i < 4; ++i) {
        h0v[i] = h0[(base + 4*q + i) * H_DIM + c];
        h1v[i] = h0[(base + 4*q + i) * H_DIM + c + 16];
    }

    // ---- x for t=0 (A-layout source: quad 0 lane m holds x[m][0..7]) ----
    float4 xA = {0,0,0,0}, xB = {0,0,0,0};
    if (q == 0) {
        const float4* xp = (const float4*)(x + (size_t)(base + c) * F_IN);
        xA = xp[0]; xB = xp[1];
    }

    // preheader: pack h0 -> LDS, issue A-frag read (rotated across loop)
#pragma unroll
    for (int i = 0; i < 4; ++i) {
        int row = 4*q + i;
        hbuf[row * 36 + c]      = packhl(h0v[i]);
        hbuf[row * 36 + c + 16] = packhl(h1v[i]);
    }
    asm volatile("" ::: "memory");
    uint4 ha4 = ((const uint4*)&hbuf[c * 36 + 8 * q])[0];
    uint4 hb4 = ((const uint4*)&hbuf[c * 36 + 8 * q])[1];

#pragma unroll 1
    for (int t = 0; t < T_STEPS; ++t) {
        // prefetch next step's x (used next iteration; latency overlapped)
        float4 xnA = xA, xnB = xB;
        if (t + 1 < T_STEPS && q == 0) {
            const float4* xp = (const float4*)(x + (size_t)(t + 1) * (N_NODES * F_IN)
                                                 + (size_t)(base + c) * F_IN);
            xnA = xp[0]; xnB = xp[1];
        }

        bf16x8 ahh, ahl; unpack2(ha4, hb4, ahh, ahl);

        // x A-frag (quads 1-3 are zero)
        float xv[8] = {xA.x, xA.y, xA.z, xA.w, xB.x, xB.y, xB.z, xB.w};
        bf16x8 axh, axl; split_pack8(xv, axh, axl);

        // ---- z, r pre-activations (biases seeded in acc) ----
        f32x4 az0 = {bz0,bz0,bz0,bz0}, az1 = {bz1,bz1,bz1,bz1};
        f32x4 ar0 = {br0,br0,br0,br0}, ar1 = {br1,br1,br1,br1};
        az0 = MFMA(axh, Xzh[0], az0); az1 = MFMA(axh, Xzh[1], az1);
        ar0 = MFMA(axh, Xrh[0], ar0); ar1 = MFMA(axh, Xrh[1], ar1);
        az0 = MFMA(axl, Xzh[0], az0); az1 = MFMA(axl, Xzh[1], az1);
        ar0 = MFMA(axl, Xrh[0], ar0); ar1 = MFMA(axl, Xrh[1], ar1);
        az0 = MFMA(axh, Xzl[0], az0); az1 = MFMA(axh, Xzl[1], az1);
        ar0 = MFMA(axh, Xrl[0], ar0); ar1 = MFMA(axh, Xrl[1], ar1);
        az0 = MFMA(ahh, Bzh[0], az0); az1 = MFMA(ahh, Bzh[1], az1);
        ar0 = MFMA(ahh, Brh[0], ar0); ar1 = MFMA(ahh, Brh[1], ar1);
        az0 = MFMA(ahl, Bzh[0], az0); az1 = MFMA(ahl, Bzh[1], az1);
        ar0 = MFMA(ahl, Brh[0], ar0); ar1 = MFMA(ahl, Brh[1], ar1);
        az0 = MFMA(ahh, Bzl[0], az0); az1 = MFMA(ahh, Bzl[1], az1);
        ar0 = MFMA(ahh, Brl[0], ar0); ar1 = MFMA(ahh, Brl[1], ar1);

        f32x4 zv0, zv1, rv0, rv1;
#pragma unroll
        for (int i = 0; i < 4; ++i) {
            zv0[i] = sigmoid_f(az0[i]); zv1[i] = sigmoid_f(az1[i]);
            rv0[i] = sigmoid_f(ar0[i]); rv1[i] = sigmoid_f(ar1[i]);
        }

        // r*h (C-layout) -> LDS
#pragma unroll
        for (int i = 0; i < 4; ++i) {
            int row = 4*q + i;
            rbuf[row * 36 + c]      = packhl(rv0[i] * h0v[i]);
            rbuf[row * 36 + c + 16] = packhl(rv1[i] * h1v[i]);
        }
        asm volatile("" ::: "memory");

        // h_tilde x-part overlaps the rbuf round-trip latency
        f32x4 ah0 = {bh0,bh0,bh0,bh0}, ah1 = {bh1,bh1,bh1,bh1};
        ah0 = MFMA(axh, Xhh2[0], ah0); ah1 = MFMA(axh, Xhh2[1], ah1);
        ah0 = MFMA(axl, Xhh2[0], ah0); ah1 = MFMA(axl, Xhh2[1], ah1);
        ah0 = MFMA(axh, Xhl2[0], ah0); ah1 = MFMA(axh, Xhl2[1], ah1);

        uint4 ra4 = ((const uint4*)&rbuf[c * 36 + 8 * q])[0];
        uint4 rb4 = ((const uint4*)&rbuf[c * 36 + 8 * q])[1];
        bf16x8 arh, arl; unpack2(ra4, rb4, arh, arl);

        ah0 = MFMA(arh, Bhh2[0], ah0); ah1 = MFMA(arh, Bhh2[1], ah1);
        ah0 = MFMA(arl, Bhh2[0], ah0); ah1 = MFMA(arl, Bhh2[1], ah1);
        ah0 = MFMA(arh, Bhl2[0], ah0); ah1 = MFMA(arh, Bhl2[1], ah1);

        // blend
#pragma unroll
        for (int i = 0; i < 4; ++i) {
            float th0 = tanh_f(ah0[i]);
            float th1 = tanh_f(ah1[i]);
            h0v[i] = zv0[i] * h0v[i] + (1.0f - zv0[i]) * th0;
            h1v[i] = zv1[i] * h1v[i] + (1.0f - zv1[i]) * th1;
        }

        // write next step's h A-frag source + issue the read now; its
        // latency hides behind the head shuffles below.
        if (t + 1 < T_STEPS) {
#pragma unroll
            for (int i = 0; i < 4; ++i) {
                int row = 4*q + i;
                hbuf[row * 36 + c]      = packhl(h0v[i]);
                hbuf[row * 36 + c + 16] = packhl(h1v[i]);
            }
            asm volatile("" ::: "memory");
            ha4 = ((const uint4*)&hbuf[c * 36 + 8 * q])[0];
            hb4 = ((const uint4*)&hbuf[c * 36 + 8 * q])[1];
        }

        // ---- fused head: leaky -> @W1 -> leaky -> @W2, wave reduce ----
        float rsum[4];
#pragma unroll
        for (int i = 0; i < 4; ++i)
            rsum[i] = leaky_f(h0v[i]) * w1a + leaky_f(h1v[i]) * w1b;
#pragma unroll
        for (int m = 1; m <= 8; m <<= 1) {
#pragma unroll
            for (int i = 0; i < 4; ++i) rsum[i] += __shfl_xor(rsum[i], m);
        }
        float s = 0.0f;
#pragma unroll
        for (int i = 0; i < 4; ++i) s += leaky_f(rsum[i] + b1s) * w2v[i];
        s += __shfl_xor(s, 16);
        s += __shfl_xor(s, 32);
        if (l == 0) outacc[t] = s;   // per-block LDS, no atomic, no barrier

        xA = xnA; xB = xnB;
    }

    // h_fin
#pragma unroll
    for (int i = 0; i < 4; ++i) {
        out[T_STEPS + (base + 4*q + i) * H_DIM + c]      = h0v[i];
        out[T_STEPS + (base + 4*q + i) * H_DIM + c + 16] = h1v[i];
    }

    // one padded atomic per t per block (64 distinct cachelines)
    atomicAdd(&ws[l * WS_STRIDE], outacc[l]);
}

extern "C" void kernel_launch(void* const* d_in, const int* in_sizes, int n_in,
                              void* d_out, int out_size, void* d_ws, size_t ws_size,
                              hipStream_t stream) {
    const float* x    = (const float*)d_in[0];
    // d_in[1] edge_index (int64), d_in[2] edge_weight: dead for K=1 ChebConv
    const float* h0   = (const float*)d_in[3];
    const float* Wxz  = (const float*)d_in[4];
    const float* bxz  = (const float*)d_in[5];
    const float* Whz  = (const float*)d_in[6];
    const float* bhz  = (const float*)d_in[7];
    const float* Wxr  = (const float*)d_in[8];
    const float* bxr  = (const float*)d_in[9];
    const float* Whr  = (const float*)d_in[10];
    const float* bhr  = (const float*)d_in[11];
    const float* Wxh  = (const float*)d_in[12];
    const float* bxh  = (const float*)d_in[13];
    const float* Whh  = (const float*)d_in[14];
    const float* bhh  = (const float*)d_in[15];
    const float* W1   = (const float*)d_in[16];
    const float* b1   = (const float*)d_in[17];
    const float* W2   = (const float*)d_in[18];
    const float* b2   = (const float*)d_in[19];
    float* out = (float*)d_out;
    float* ws  = (float*)d_ws;

    init_ws_kernel<<<(T_STEPS * WS_STRIDE + 255) / 256, 256, 0, stream>>>(ws);

    const int grid = N_NODES / 16;  // 1250 one-wave blocks, exact
    rgcn_mfma_kernel<<<grid, 64, 0, stream>>>(
        x, h0, Wxz, bxz, Whz, bhz, Wxr, bxr, Whr, bhr,
        Wxh, bxh, Whh, bhh, W1, b1, W2, ws, out);

    final_kernel<<<1, 64, 0, stream>>>(ws, b2, out);
}

// Round 5
// 261.633 us; speedup vs baseline: 3.0369x; 1.2160x over previous
//
#include <hip/hip_runtime.h>

// T=64, N=20000, F=8, H=32. edge_index/edge_weight dead (K=1 ChebConv).
// R5: 2 waves/block split by output-column tile (wave w owns cols [16w,16w+16)).
// Per step: x-part MFMAs pre-barrier; h C->A via LDS round-trip (packed bf16
// hi|lo words, truncation split + v_perm_b32); two block barriers/step.
// Head: per-wave partial -> LDS pacc; combine for step t-1 rides step t's
// barrier A (safe: pacc writes are post-barrier-B, combine reads pre-B).
#define T_STEPS 64
#define N_NODES 20000
#define F_IN    8
#define H_DIM   32
#define NEG_SLOPE 0.01f
#define WS_STRIDE 32   // floats; one 128B cacheline per t

typedef __attribute__((ext_vector_type(8))) short bf16x8;
typedef __attribute__((ext_vector_type(4))) float f32x4;

#define MFMA(a, b, c) __builtin_amdgcn_mfma_f32_16x16x32_bf16((a), (b), (c), 0, 0, 0)

// ---------- RNE helpers (weights only, outside the hot loop) ----------
__device__ __forceinline__ unsigned short f2bf(float f) {
    unsigned u = __float_as_uint(f);
    u += 0x7FFFu + ((u >> 16) & 1u);          // RNE
    return (unsigned short)(u >> 16);
}
__device__ __forceinline__ float bf2f(unsigned short s) {
    return __uint_as_float(((unsigned)s) << 16);
}
__device__ __forceinline__ void split_pack8_rne(const float* v, bf16x8& hi, bf16x8& lo) {
    union { unsigned u[4]; bf16x8 v8; } H, L;
#pragma unroll
    for (int p = 0; p < 4; ++p) {
        float a = v[2*p], b = v[2*p+1];
        unsigned short ha = f2bf(a), hb = f2bf(b);
        unsigned short la = f2bf(a - bf2f(ha)), lb = f2bf(b - bf2f(hb));
        H.u[p] = (unsigned)ha | ((unsigned)hb << 16);
        L.u[p] = (unsigned)la | ((unsigned)lb << 16);
    }
    hi = H.v8; lo = L.v8;
}
// B-frag (K=32 weight, row-major [K][H]): lane holds col, k = 8*q + j
__device__ __forceinline__ void load_wfrag32(const float* __restrict__ W, int col, int q,
                                             bf16x8& hi, bf16x8& lo) {
    float v[8];
#pragma unroll
    for (int j = 0; j < 8; ++j) v[j] = W[(8*q + j) * H_DIM + col];
    split_pack8_rne(v, hi, lo);
}
// B-frag for K=8 weight zero-padded to K=32 (only quad 0 holds data)
__device__ __forceinline__ void load_wfrag8(const float* __restrict__ W, int col, int q,
                                            bf16x8& hi, bf16x8& lo) {
    float v[8];
#pragma unroll
    for (int j = 0; j < 8; ++j) v[j] = (q == 0) ? W[j * H_DIM + col] : 0.0f;
    split_pack8_rne(v, hi, lo);
}

// ---------- fast in-loop truncation split + byte perms ----------
// packed word: low16 = bf16 hi(v) (truncated), high16 = bf16 lo(v) (truncated)
__device__ __forceinline__ unsigned packhl_fast(float v) {
    unsigned u  = __float_as_uint(v);
    unsigned hi = u & 0xffff0000u;
    float    lo = v - __uint_as_float(hi);
    // out = {hi.b2, hi.b3, lo.b2, lo.b3}
    return __builtin_amdgcn_perm(__float_as_uint(lo), hi, 0x07060302u);
}
// 8 packed words -> hi-frag, lo-frag
__device__ __forceinline__ void unpack2(uint4 a, uint4 b, bf16x8& hi, bf16x8& lo) {
    union { unsigned u[4]; bf16x8 v8; } H, L;
    unsigned w[8] = {a.x, a.y, a.z, a.w, b.x, b.y, b.z, b.w};
#pragma unroll
    for (int p = 0; p < 4; ++p) {
        H.u[p] = __builtin_amdgcn_perm(w[2*p+1], w[2*p], 0x05040100u); // lo16s
        L.u[p] = __builtin_amdgcn_perm(w[2*p+1], w[2*p], 0x07060302u); // hi16s
    }
    hi = H.v8; lo = L.v8;
}
// 8 floats -> hi/lo frags directly (truncation split)
__device__ __forceinline__ void fastsplit8(const float* v, bf16x8& hi, bf16x8& lo) {
    union { unsigned u[4]; bf16x8 v8; } H, L;
    unsigned hu[8]; unsigned lu[8];
#pragma unroll
    for (int j = 0; j < 8; ++j) {
        hu[j] = __float_as_uint(v[j]) & 0xffff0000u;
        lu[j] = __float_as_uint(v[j] - __uint_as_float(hu[j]));
    }
#pragma unroll
    for (int p = 0; p < 4; ++p) {
        H.u[p] = __builtin_amdgcn_perm(hu[2*p+1], hu[2*p], 0x07060302u);
        L.u[p] = __builtin_amdgcn_perm(lu[2*p+1], lu[2*p], 0x07060302u);
    }
    hi = H.v8; lo = L.v8;
}

__device__ __forceinline__ float sigmoid_f(float x) { return 1.0f / (1.0f + __expf(-x)); }
__device__ __forceinline__ float tanh_f(float x)    { return 1.0f - 2.0f / (1.0f + __expf(2.0f * x)); }
__device__ __forceinline__ float leaky_f(float x)   { return x > 0.0f ? x : NEG_SLOPE * x; }

__global__ void init_ws_kernel(float* __restrict__ ws) {
    int i = blockIdx.x * blockDim.x + threadIdx.x;
    if (i < T_STEPS * WS_STRIDE) ws[i] = 0.0f;
}

__global__ void final_kernel(const float* __restrict__ ws, const float* __restrict__ b2,
                             float* __restrict__ out) {
    int t = threadIdx.x;
    if (t < T_STEPS) out[t] = ws[t * WS_STRIDE] + b2[0];
}

__global__ __launch_bounds__(128) void rgcn_mfma_kernel(
    const float* __restrict__ x,    // [T,N,F]
    const float* __restrict__ h0,   // [N,H]
    const float* __restrict__ Wxz, const float* __restrict__ bxz,
    const float* __restrict__ Whz, const float* __restrict__ bhz,
    const float* __restrict__ Wxr, const float* __restrict__ bxr,
    const float* __restrict__ Whr, const float* __restrict__ bhr,
    const float* __restrict__ Wxh, const float* __restrict__ bxh,
    const float* __restrict__ Whh, const float* __restrict__ bhh,
    const float* __restrict__ W1,  const float* __restrict__ b1,
    const float* __restrict__ W2,
    float* __restrict__ ws,         // [T*WS_STRIDE] accumulators (pre-zeroed)
    float* __restrict__ out)        // [T] then [N,H]
{
    const int tid = threadIdx.x;
    const int w   = tid >> 6;        // wave id 0/1 -> column tile
    const int l   = tid & 63;        // lane
    const int c   = l & 15;
    const int q   = l >> 4;
    const int base = blockIdx.x * 16;
    const int col  = c + 16 * w;     // this wave's output column

    __shared__ __align__(16) unsigned hbuf[16 * 36];  // packed h, full 32 cols
    __shared__ __align__(16) unsigned rbuf[16 * 36];  // packed r*h
    __shared__ float pacc[2][16];                     // head partials per wave
    __shared__ float outacc[T_STEPS];

    // ---- per-wave B-frags for its tile (hi/lo RNE split) ----
    bf16x8 Bzh, Bzl, Brh, Brl, Bhh, Bhl;   // Wh* (K=32)
    bf16x8 Xzh, Xzl, Xrh, Xrl, Xhh, Xhl;   // Wx* (K=8 padded)
    load_wfrag32(Whz, col, q, Bzh, Bzl);
    load_wfrag32(Whr, col, q, Brh, Brl);
    load_wfrag32(Whh, col, q, Bhh, Bhl);
    load_wfrag8 (Wxz, col, q, Xzh, Xzl);
    load_wfrag8 (Wxr, col, q, Xrh, Xrl);
    load_wfrag8 (Wxh, col, q, Xhh, Xhl);

    const float bz  = bxz[col] + bhz[col];
    const float br  = bxr[col] + bhr[col];
    const float bh  = bxh[col] + bhh[col];
    const float w1l = W1[col];
    const float b1s = b1[0];
    const float w2l = (w == 0 && l < 16) ? W2[base + l] : 0.0f;

    // h state (C-layout): lane holds rows 4q+i, its column `col`
    float hv[4];
#pragma unroll
    for (int i = 0; i < 4; ++i) {
        hv[i] = h0[(base + 4*q + i) * H_DIM + col];
        hbuf[(4*q + i) * 36 + col] = packhl_fast(hv[i]);
    }

    // x A-frag for t=0 (quad 0 lanes hold node base+c's 8 features)
    float4 x0 = {0,0,0,0}, x1 = {0,0,0,0};
    if (q == 0) {
        const float4* xp = (const float4*)(x + (size_t)(base + c) * F_IN);
        x0 = xp[0]; x1 = xp[1];
    }
    float xv[8] = {x0.x, x0.y, x0.z, x0.w, x1.x, x1.y, x1.z, x1.w};
    bf16x8 fx_h, fx_l; fastsplit8(xv, fx_h, fx_l);

    const f32x4 zero4 = {0.0f, 0.0f, 0.0f, 0.0f};

#pragma unroll 1
    for (int t = 0; t < T_STEPS; ++t) {
        // issue next step's x load early (full iteration to cover latency)
        float4 nx0 = {0,0,0,0}, nx1 = {0,0,0,0};
        if (t + 1 < T_STEPS && q == 0) {
            const float4* xp = (const float4*)(x + (size_t)(t + 1) * (N_NODES * F_IN)
                                                 + (size_t)(base + c) * F_IN);
            nx0 = xp[0]; nx1 = xp[1];
        }

        // ---- x-part MFMAs (independent of h; pre-barrier) ----
        f32x4 azx = {bz, bz, bz, bz};
        f32x4 arx = {br, br, br, br};
        f32x4 ahx = {bh, bh, bh, bh};
        azx = MFMA(fx_h, Xzh, azx); arx = MFMA(fx_h, Xrh, arx); ahx = MFMA(fx_h, Xhh, ahx);
        azx = MFMA(fx_l, Xzh, azx); arx = MFMA(fx_l, Xrh, arx); ahx = MFMA(fx_l, Xhh, ahx);
        azx = MFMA(fx_h, Xzl, azx); arx = MFMA(fx_h, Xrl, arx); ahx = MFMA(fx_h, Xhl, ahx);

        __syncthreads();   // barrier A: hbuf (and prev pacc) ready

        // full-h A-frag: lane row = c, k = 8q..8q+7
        uint4 ha4 = ((const uint4*)&hbuf[c * 36 + 8 * q])[0];
        uint4 hb4 = ((const uint4*)&hbuf[c * 36 + 8 * q])[1];
        bf16x8 fh_h, fh_l; unpack2(ha4, hb4, fh_h, fh_l);

        // wave 0 combines previous step's head partials (reads pre-barrier-B)
        if (w == 0 && t > 0) {
            float pv = pacc[0][c] + pacc[1][c] + b1s;
            float a2 = leaky_f(pv) * w2l;
            a2 += __shfl_xor(a2, 1); a2 += __shfl_xor(a2, 2);
            a2 += __shfl_xor(a2, 4); a2 += __shfl_xor(a2, 8);
            if (l == 0) outacc[t - 1] = a2;
        }

        // ---- h-part MFMAs for z, r ----
        f32x4 azh = zero4, arh = zero4;
        azh = MFMA(fh_h, Bzh, azh); arh = MFMA(fh_h, Brh, arh);
        azh = MFMA(fh_l, Bzh, azh); arh = MFMA(fh_l, Brh, arh);
        azh = MFMA(fh_h, Bzl, azh); arh = MFMA(fh_h, Brl, arh);

        float zv[4];
#pragma unroll
        for (int i = 0; i < 4; ++i) {
            zv[i] = sigmoid_f(azx[i] + azh[i]);
            float r = sigmoid_f(arx[i] + arh[i]);
            rbuf[(4*q + i) * 36 + col] = packhl_fast(r * hv[i]);
        }

        __syncthreads();   // barrier B: rbuf ready

        uint4 ra4 = ((const uint4*)&rbuf[c * 36 + 8 * q])[0];
        uint4 rb4 = ((const uint4*)&rbuf[c * 36 + 8 * q])[1];
        bf16x8 fr_h, fr_l; unpack2(ra4, rb4, fr_h, fr_l);

        f32x4 ahr = zero4;
        ahr = MFMA(fr_h, Bhh, ahr);
        ahr = MFMA(fr_l, Bhh, ahr);
        ahr = MFMA(fr_h, Bhl, ahr);

        // blend + write next h + head partial
        float pl[4];
#pragma unroll
        for (int i = 0; i < 4; ++i) {
            float th = tanh_f(ahx[i] + ahr[i]);
            float hn = zv[i] * hv[i] + (1.0f - zv[i]) * th;
            hv[i] = hn;
            hbuf[(4*q + i) * 36 + col] = packhl_fast(hn);
            pl[i] = leaky_f(hn) * w1l;
        }
#pragma unroll
        for (int m = 1; m <= 8; m <<= 1) {
#pragma unroll
            for (int i = 0; i < 4; ++i) pl[i] += __shfl_xor(pl[i], m);
        }
        if (c == 0) {
#pragma unroll
            for (int i = 0; i < 4; ++i) pacc[w][4*q + i] = pl[i];
        }

        // pack next x frag
        float nxv[8] = {nx0.x, nx0.y, nx0.z, nx0.w, nx1.x, nx1.y, nx1.z, nx1.w};
        fastsplit8(nxv, fx_h, fx_l);
    }

    __syncthreads();   // final pacc visible

    if (w == 0) {
        // combine for t = T-1
        float pv = pacc[0][c] + pacc[1][c] + b1s;
        float a2 = leaky_f(pv) * w2l;
        a2 += __shfl_xor(a2, 1); a2 += __shfl_xor(a2, 2);
        a2 += __shfl_xor(a2, 4); a2 += __shfl_xor(a2, 8);
        if (l == 0) outacc[T_STEPS - 1] = a2;
        // one padded atomic per t per block (same-wave LDS write->read is in-order)
        atomicAdd(&ws[l * WS_STRIDE], outacc[l]);
    }

    // h_fin: each wave writes its own columns
#pragma unroll
    for (int i = 0; i < 4; ++i)
        out[T_STEPS + (base + 4*q + i) * H_DIM + col] = hv[i];
}

extern "C" void kernel_launch(void* const* d_in, const int* in_sizes, int n_in,
                              void* d_out, int out_size, void* d_ws, size_t ws_size,
                              hipStream_t stream) {
    const float* x    = (const float*)d_in[0];
    // d_in[1] edge_index (int64), d_in[2] edge_weight: dead for K=1 ChebConv
    const float* h0   = (const float*)d_in[3];
    const float* Wxz  = (const float*)d_in[4];
    const float* bxz  = (const float*)d_in[5];
    const float* Whz  = (const float*)d_in[6];
    const float* bhz  = (const float*)d_in[7];
    const float* Wxr  = (const float*)d_in[8];
    const float* bxr  = (const float*)d_in[9];
    const float* Whr  = (const float*)d_in[10];
    const float* bhr  = (const float*)d_in[11];
    const float* Wxh  = (const float*)d_in[12];
    const float* bxh  = (const float*)d_in[13];
    const float* Whh  = (const float*)d_in[14];
    const float* bhh  = (const float*)d_in[15];
    const float* W1   = (const float*)d_in[16];
    const float* b1   = (const float*)d_in[17];
    const float* W2   = (const float*)d_in[18];
    const float* b2   = (const float*)d_in[19];
    float* out = (float*)d_out;
    float* ws  = (float*)d_ws;

    init_ws_kernel<<<(T_STEPS * WS_STRIDE + 255) / 256, 256, 0, stream>>>(ws);

    const int grid = N_NODES / 16;  // 1250 blocks x 2 waves
    rgcn_mfma_kernel<<<grid, 128, 0, stream>>>(
        x, h0, Wxz, bxz, Whz, bhz, Wxr, bxr, Whr, bhr,
        Wxh, bxh, Whh, bhh, W1, b1, W2, ws, out);

    final_kernel<<<1, 64, 0, stream>>>(ws, b2, out);
}

// Round 6
// 256.088 us; speedup vs baseline: 3.1027x; 1.0217x over previous
//
#include <hip/hip_runtime.h>

// T=64, N=20000, F=8, H=32. edge_index/edge_weight dead (K=1 ChebConv).
// R6 = R5 + __launch_bounds__(128, 2). R5's VGPR_Count=64 showed the
// allocator (chasing unusable 8-wave occupancy) parked the 48 weight-frag
// VGPRs in AGPRs and re-read them before every MFMA (~4x VALU bloat:
// measured 785 VALU inst/wave/step vs ~190 in source). min-waves=2 lifts
// the budget to 256 VGPRs; only 2500 waves exist (2.44/SIMD) so nothing
// is lost. Structure: 2 waves/block, wave w owns output cols [16w,16w+16);
// x-part MFMAs pre-barrier; h C->A via LDS round-trip (packed bf16 hi|lo,
// truncation split + v_perm); head partial combine rides next step's
// barrier A; one padded global atomic per t per block.
#define T_STEPS 64
#define N_NODES 20000
#define F_IN    8
#define H_DIM   32
#define NEG_SLOPE 0.01f
#define WS_STRIDE 32   // floats; one 128B cacheline per t

typedef __attribute__((ext_vector_type(8))) short bf16x8;
typedef __attribute__((ext_vector_type(4))) float f32x4;

#define MFMA(a, b, c) __builtin_amdgcn_mfma_f32_16x16x32_bf16((a), (b), (c), 0, 0, 0)

// ---------- RNE helpers (weights only, outside the hot loop) ----------
__device__ __forceinline__ unsigned short f2bf(float f) {
    unsigned u = __float_as_uint(f);
    u += 0x7FFFu + ((u >> 16) & 1u);          // RNE
    return (unsigned short)(u >> 16);
}
__device__ __forceinline__ float bf2f(unsigned short s) {
    return __uint_as_float(((unsigned)s) << 16);
}
__device__ __forceinline__ void split_pack8_rne(const float* v, bf16x8& hi, bf16x8& lo) {
    union { unsigned u[4]; bf16x8 v8; } H, L;
#pragma unroll
    for (int p = 0; p < 4; ++p) {
        float a = v[2*p], b = v[2*p+1];
        unsigned short ha = f2bf(a), hb = f2bf(b);
        unsigned short la = f2bf(a - bf2f(ha)), lb = f2bf(b - bf2f(hb));
        H.u[p] = (unsigned)ha | ((unsigned)hb << 16);
        L.u[p] = (unsigned)la | ((unsigned)lb << 16);
    }
    hi = H.v8; lo = L.v8;
}
// B-frag (K=32 weight, row-major [K][H]): lane holds col, k = 8*q + j
__device__ __forceinline__ void load_wfrag32(const float* __restrict__ W, int col, int q,
                                             bf16x8& hi, bf16x8& lo) {
    float v[8];
#pragma unroll
    for (int j = 0; j < 8; ++j) v[j] = W[(8*q + j) * H_DIM + col];
    split_pack8_rne(v, hi, lo);
}
// B-frag for K=8 weight zero-padded to K=32 (only quad 0 holds data)
__device__ __forceinline__ void load_wfrag8(const float* __restrict__ W, int col, int q,
                                            bf16x8& hi, bf16x8& lo) {
    float v[8];
#pragma unroll
    for (int j = 0; j < 8; ++j) v[j] = (q == 0) ? W[j * H_DIM + col] : 0.0f;
    split_pack8_rne(v, hi, lo);
}

// ---------- fast in-loop truncation split + byte perms ----------
// packed word: low16 = bf16 hi(v) (truncated), high16 = bf16 lo(v)
__device__ __forceinline__ unsigned packhl_fast(float v) {
    unsigned u  = __float_as_uint(v);
    unsigned hi = u & 0xffff0000u;
    float    lo = v - __uint_as_float(hi);
    return __builtin_amdgcn_perm(__float_as_uint(lo), hi, 0x07060302u);
}
// 8 packed words -> hi-frag, lo-frag
__device__ __forceinline__ void unpack2(uint4 a, uint4 b, bf16x8& hi, bf16x8& lo) {
    union { unsigned u[4]; bf16x8 v8; } H, L;
    unsigned w[8] = {a.x, a.y, a.z, a.w, b.x, b.y, b.z, b.w};
#pragma unroll
    for (int p = 0; p < 4; ++p) {
        H.u[p] = __builtin_amdgcn_perm(w[2*p+1], w[2*p], 0x05040100u);
        L.u[p] = __builtin_amdgcn_perm(w[2*p+1], w[2*p], 0x07060302u);
    }
    hi = H.v8; lo = L.v8;
}
// 8 floats -> hi/lo frags directly (truncation split)
__device__ __forceinline__ void fastsplit8(const float* v, bf16x8& hi, bf16x8& lo) {
    union { unsigned u[4]; bf16x8 v8; } H, L;
    unsigned hu[8]; unsigned lu[8];
#pragma unroll
    for (int j = 0; j < 8; ++j) {
        hu[j] = __float_as_uint(v[j]) & 0xffff0000u;
        lu[j] = __float_as_uint(v[j] - __uint_as_float(hu[j]));
    }
#pragma unroll
    for (int p = 0; p < 4; ++p) {
        H.u[p] = __builtin_amdgcn_perm(hu[2*p+1], hu[2*p], 0x07060302u);
        L.u[p] = __builtin_amdgcn_perm(lu[2*p+1], lu[2*p], 0x07060302u);
    }
    hi = H.v8; lo = L.v8;
}

__device__ __forceinline__ float sigmoid_f(float x) { return 1.0f / (1.0f + __expf(-x)); }
__device__ __forceinline__ float tanh_f(float x)    { return 1.0f - 2.0f / (1.0f + __expf(2.0f * x)); }
__device__ __forceinline__ float leaky_f(float x)   { return x > 0.0f ? x : NEG_SLOPE * x; }

__global__ void init_ws_kernel(float* __restrict__ ws) {
    int i = blockIdx.x * blockDim.x + threadIdx.x;
    if (i < T_STEPS * WS_STRIDE) ws[i] = 0.0f;
}

__global__ void final_kernel(const float* __restrict__ ws, const float* __restrict__ b2,
                             float* __restrict__ out) {
    int t = threadIdx.x;
    if (t < T_STEPS) out[t] = ws[t * WS_STRIDE] + b2[0];
}

__global__ __launch_bounds__(128, 2) void rgcn_mfma_kernel(
    const float* __restrict__ x,    // [T,N,F]
    const float* __restrict__ h0,   // [N,H]
    const float* __restrict__ Wxz, const float* __restrict__ bxz,
    const float* __restrict__ Whz, const float* __restrict__ bhz,
    const float* __restrict__ Wxr, const float* __restrict__ bxr,
    const float* __restrict__ Whr, const float* __restrict__ bhr,
    const float* __restrict__ Wxh, const float* __restrict__ bxh,
    const float* __restrict__ Whh, const float* __restrict__ bhh,
    const float* __restrict__ W1,  const float* __restrict__ b1,
    const float* __restrict__ W2,
    float* __restrict__ ws,         // [T*WS_STRIDE] accumulators (pre-zeroed)
    float* __restrict__ out)        // [T] then [N,H]
{
    const int tid = threadIdx.x;
    const int w   = tid >> 6;        // wave id 0/1 -> column tile
    const int l   = tid & 63;        // lane
    const int c   = l & 15;
    const int q   = l >> 4;
    const int base = blockIdx.x * 16;
    const int col  = c + 16 * w;     // this wave's output column

    __shared__ __align__(16) unsigned hbuf[16 * 36];  // packed h, full 32 cols
    __shared__ __align__(16) unsigned rbuf[16 * 36];  // packed r*h
    __shared__ float pacc[2][16];                     // head partials per wave
    __shared__ float outacc[T_STEPS];

    // ---- per-wave B-frags for its tile (hi/lo RNE split) ----
    bf16x8 Bzh, Bzl, Brh, Brl, Bhh, Bhl;   // Wh* (K=32)
    bf16x8 Xzh, Xzl, Xrh, Xrl, Xhh, Xhl;   // Wx* (K=8 padded)
    load_wfrag32(Whz, col, q, Bzh, Bzl);
    load_wfrag32(Whr, col, q, Brh, Brl);
    load_wfrag32(Whh, col, q, Bhh, Bhl);
    load_wfrag8 (Wxz, col, q, Xzh, Xzl);
    load_wfrag8 (Wxr, col, q, Xrh, Xrl);
    load_wfrag8 (Wxh, col, q, Xhh, Xhl);

    const float bz  = bxz[col] + bhz[col];
    const float br  = bxr[col] + bhr[col];
    const float bh  = bxh[col] + bhh[col];
    const float w1l = W1[col];
    const float b1s = b1[0];
    const float w2l = (w == 0 && l < 16) ? W2[base + l] : 0.0f;

    // h state (C-layout): lane holds rows 4q+i, its column `col`
    float hv[4];
#pragma unroll
    for (int i = 0; i < 4; ++i) {
        hv[i] = h0[(base + 4*q + i) * H_DIM + col];
        hbuf[(4*q + i) * 36 + col] = packhl_fast(hv[i]);
    }

    // x A-frag for t=0 (quad 0 lanes hold node base+c's 8 features)
    float4 x0 = {0,0,0,0}, x1 = {0,0,0,0};
    if (q == 0) {
        const float4* xp = (const float4*)(x + (size_t)(base + c) * F_IN);
        x0 = xp[0]; x1 = xp[1];
    }
    float xv[8] = {x0.x, x0.y, x0.z, x0.w, x1.x, x1.y, x1.z, x1.w};
    bf16x8 fx_h, fx_l; fastsplit8(xv, fx_h, fx_l);

    const f32x4 zero4 = {0.0f, 0.0f, 0.0f, 0.0f};

#pragma unroll 1
    for (int t = 0; t < T_STEPS; ++t) {
        // branchless next-x prefetch (t=T-1 reloads last row, discarded)
        float4 nx0 = {0,0,0,0}, nx1 = {0,0,0,0};
        {
            int tt = (t + 1 < T_STEPS) ? (t + 1) : (T_STEPS - 1);
            if (q == 0) {
                const float4* xp = (const float4*)(x + (size_t)tt * (N_NODES * F_IN)
                                                     + (size_t)(base + c) * F_IN);
                nx0 = xp[0]; nx1 = xp[1];
            }
        }

        // ---- x-part MFMAs (independent of h; pre-barrier) ----
        f32x4 azx = {bz, bz, bz, bz};
        f32x4 arx = {br, br, br, br};
        f32x4 ahx = {bh, bh, bh, bh};
        azx = MFMA(fx_h, Xzh, azx); arx = MFMA(fx_h, Xrh, arx); ahx = MFMA(fx_h, Xhh, ahx);
        azx = MFMA(fx_l, Xzh, azx); arx = MFMA(fx_l, Xrh, arx); ahx = MFMA(fx_l, Xhh, ahx);
        azx = MFMA(fx_h, Xzl, azx); arx = MFMA(fx_h, Xrl, arx); ahx = MFMA(fx_h, Xhl, ahx);

        __syncthreads();   // barrier A: hbuf (and prev pacc) ready

        // full-h A-frag: lane row = c, k = 8q..8q+7
        uint4 ha4 = ((const uint4*)&hbuf[c * 36 + 8 * q])[0];
        uint4 hb4 = ((const uint4*)&hbuf[c * 36 + 8 * q])[1];
        bf16x8 fh_h, fh_l; unpack2(ha4, hb4, fh_h, fh_l);

        // wave 0 combines previous step's head partials (reads pre-barrier-B)
        if (w == 0 && t > 0) {
            float pv = pacc[0][c] + pacc[1][c] + b1s;
            float a2 = leaky_f(pv) * w2l;
            a2 += __shfl_xor(a2, 1); a2 += __shfl_xor(a2, 2);
            a2 += __shfl_xor(a2, 4); a2 += __shfl_xor(a2, 8);
            if (l == 0) outacc[t - 1] = a2;
        }

        // ---- h-part MFMAs for z, r ----
        f32x4 azh = zero4, arh = zero4;
        azh = MFMA(fh_h, Bzh, azh); arh = MFMA(fh_h, Brh, arh);
        azh = MFMA(fh_l, Bzh, azh); arh = MFMA(fh_l, Brh, arh);
        azh = MFMA(fh_h, Bzl, azh); arh = MFMA(fh_h, Brl, arh);

        float zv[4];
#pragma unroll
        for (int i = 0; i < 4; ++i) {
            zv[i] = sigmoid_f(azx[i] + azh[i]);
            float r = sigmoid_f(arx[i] + arh[i]);
            rbuf[(4*q + i) * 36 + col] = packhl_fast(r * hv[i]);
        }

        __syncthreads();   // barrier B: rbuf ready

        uint4 ra4 = ((const uint4*)&rbuf[c * 36 + 8 * q])[0];
        uint4 rb4 = ((const uint4*)&rbuf[c * 36 + 8 * q])[1];
        bf16x8 fr_h, fr_l; unpack2(ra4, rb4, fr_h, fr_l);

        f32x4 ahr = zero4;
        ahr = MFMA(fr_h, Bhh, ahr);
        ahr = MFMA(fr_l, Bhh, ahr);
        ahr = MFMA(fr_h, Bhl, ahr);

        // blend + write next h + head partial
        float pl[4];
#pragma unroll
        for (int i = 0; i < 4; ++i) {
            float th = tanh_f(ahx[i] + ahr[i]);
            float hn = zv[i] * hv[i] + (1.0f - zv[i]) * th;
            hv[i] = hn;
            hbuf[(4*q + i) * 36 + col] = packhl_fast(hn);
            pl[i] = leaky_f(hn) * w1l;
        }
#pragma unroll
        for (int m = 1; m <= 8; m <<= 1) {
#pragma unroll
            for (int i = 0; i < 4; ++i) pl[i] += __shfl_xor(pl[i], m);
        }
        if (c == 0) {
#pragma unroll
            for (int i = 0; i < 4; ++i) pacc[w][4*q + i] = pl[i];
        }

        // pack next x frag
        float nxv[8] = {nx0.x, nx0.y, nx0.z, nx0.w, nx1.x, nx1.y, nx1.z, nx1.w};
        fastsplit8(nxv, fx_h, fx_l);
    }

    __syncthreads();   // final pacc visible

    if (w == 0) {
        // combine for t = T-1
        float pv = pacc[0][c] + pacc[1][c] + b1s;
        float a2 = leaky_f(pv) * w2l;
        a2 += __shfl_xor(a2, 1); a2 += __shfl_xor(a2, 2);
        a2 += __shfl_xor(a2, 4); a2 += __shfl_xor(a2, 8);
        if (l == 0) outacc[T_STEPS - 1] = a2;
        // one padded atomic per t per block (same-wave LDS write->read in-order)
        atomicAdd(&ws[l * WS_STRIDE], outacc[l]);
    }

    // h_fin: each wave writes its own columns
#pragma unroll
    for (int i = 0; i < 4; ++i)
        out[T_STEPS + (base + 4*q + i) * H_DIM + col] = hv[i];
}

extern "C" void kernel_launch(void* const* d_in, const int* in_sizes, int n_in,
                              void* d_out, int out_size, void* d_ws, size_t ws_size,
                              hipStream_t stream) {
    const float* x    = (const float*)d_in[0];
    // d_in[1] edge_index (int64), d_in[2] edge_weight: dead for K=1 ChebConv
    const float* h0   = (const float*)d_in[3];
    const float* Wxz  = (const float*)d_in[4];
    const float* bxz  = (const float*)d_in[5];
    const float* Whz  = (const float*)d_in[6];
    const float* bhz  = (const float*)d_in[7];
    const float* Wxr  = (const float*)d_in[8];
    const float* bxr  = (const float*)d_in[9];
    const float* Whr  = (const float*)d_in[10];
    const float* bhr  = (const float*)d_in[11];
    const float* Wxh  = (const float*)d_in[12];
    const float* bxh  = (const float*)d_in[13];
    const float* Whh  = (const float*)d_in[14];
    const float* bhh  = (const float*)d_in[15];
    const float* W1   = (const float*)d_in[16];
    const float* b1   = (const float*)d_in[17];
    const float* W2   = (const float*)d_in[18];
    const float* b2   = (const float*)d_in[19];
    float* out = (float*)d_out;
    float* ws  = (float*)d_ws;

    init_ws_kernel<<<(T_STEPS * WS_STRIDE + 255) / 256, 256, 0, stream>>>(ws);

    const int grid = N_NODES / 16;  // 1250 blocks x 2 waves
    rgcn_mfma_kernel<<<grid, 128, 0, stream>>>(
        x, h0, Wxz, bxz, Whz, bhz, Wxr, bxr, Whr, bhr,
        Wxh, bxh, Whh, bhh, W1, b1, W2, ws, out);

    final_kernel<<<1, 64, 0, stream>>>(ws, b2, out);
}